// Round 3
// baseline (592.101 us; speedup 1.0000x reference)
//
#include <hip/hip_runtime.h>
#include <hip/hip_bf16.h>

// PCGraphConv: iterative predictive-coding message passing.
// N_V=2000, N_E=500000, BATCH=32, T=5, lr=0.1, sensory = first 784 vertices.
// All float I/O is fp32 (established R1/R2: bf16 read gave NaN; bf16 write gave
// the scrambled-pair error signature). Internal state fp32.
// Counting-sort edges into CSR-by-dst and CSR-by-src each call (ws re-poisoned),
// values kept [vertex][batch] f32 so fx[src]/err[dst] gathers are 128B row reads.
// One wave per vertex (32 batch lanes x 2 edge strides, shfl_xor combine).
// CSR entry packed (bf16(w) << 16) | neighbor -> 4B/edge/direction, ws ~4.6MB.

#define N_V     2000
#define N_SENS  784
#define N_E     500000
#define T_STEPS 5
#define LR_VAL  0.1f
#define NVB     (N_V * 32)   // 64000

__device__ __forceinline__ float bits_to_f32(unsigned u) {
    union { unsigned u; float f; } c; c.u = u; return c.f;
}
__device__ __forceinline__ unsigned f32_to_bits(float f) {
    union { float f; unsigned u; } c; c.f = f; return c.u;
}

__global__ void k_zero_i32(int* a, int n) {
    int t = blockIdx.x * blockDim.x + threadIdx.x;
    if (t < n) a[t] = 0;
}

__global__ void k_hist(const int* __restrict__ src, const int* __restrict__ dst,
                       int* cnt_dst, int* cnt_src) {
    int e = blockIdx.x * blockDim.x + threadIdx.x;
    if (e < N_E) {
        atomicAdd(&cnt_dst[dst[e]], 1);
        atomicAdd(&cnt_src[src[e]], 1);
    }
}

// One block, 1024 threads: exclusive scan of 2000 counts (x2 arrays).
// Writes row_ptr[0..2000]; resets cnt[] to exclusive offsets (scatter cursors).
__global__ __launch_bounds__(1024) void k_scan(int* cnt_a, int* rp_a,
                                               int* cnt_b, int* rp_b) {
    __shared__ int sh[1024];
    int t = threadIdx.x;
    for (int pass = 0; pass < 2; ++pass) {
        int* cnt = pass ? cnt_b : cnt_a;
        int* rp  = pass ? rp_b  : rp_a;
        int i0 = 2 * t, i1 = 2 * t + 1;
        int c0 = (i0 < N_V) ? cnt[i0] : 0;
        int c1 = (i1 < N_V) ? cnt[i1] : 0;
        __syncthreads();
        sh[t] = c0 + c1;
        __syncthreads();
        for (int off = 1; off < 1024; off <<= 1) {
            int v = (t >= off) ? sh[t - off] : 0;
            __syncthreads();
            sh[t] += v;
            __syncthreads();
        }
        int incl = sh[t];
        int e0 = incl - (c0 + c1);
        int e1 = e0 + c0;
        if (i0 <= N_V) rp[i0] = e0;
        if (i1 <= N_V) rp[i1] = e1;
        if (i0 < N_V) cnt[i0] = e0;
        if (i1 < N_V) cnt[i1] = e1;
    }
}

// Build packed CSR entries: (bf16_weight_bits << 16) | neighbor_vertex.
__global__ void k_scatter(const int* __restrict__ src, const int* __restrict__ dst,
                          const float* __restrict__ w,
                          int* cur_dst, int* cur_src,
                          unsigned* __restrict__ pk_dst, unsigned* __restrict__ pk_src) {
    int e = blockIdx.x * blockDim.x + threadIdx.x;
    if (e < N_E) {
        int s = src[e], d = dst[e];
        unsigned u = f32_to_bits(w[e]);
        unsigned wbits = (u + 0x7FFFu + ((u >> 16) & 1u)) >> 16;   // RNE to bf16
        int p = atomicAdd(&cur_dst[d], 1);
        pk_dst[p] = (wbits << 16) | (unsigned)s;
        int q = atomicAdd(&cur_src[s], 1);
        pk_src[q] = (wbits << 16) | (unsigned)d;
    }
}

// input [batch][vertex] fp32 -> internal [vertex][batch] fp32
__global__ void k_cast_in(const float* __restrict__ vin, float* __restrict__ v) {
    int t = blockIdx.x * blockDim.x + threadIdx.x;
    if (t < NVB) {
        int i = t >> 5, b = t & 31;
        v[t] = vin[b * N_V + i];
    }
}

__global__ void k_fx(const float* __restrict__ v, float* __restrict__ fx) {
    int t = blockIdx.x * blockDim.x + threadIdx.x;
    if (t < NVB) fx[t] = tanhf(v[t]);
}

// err[i][b] = v[i][b] - sum_{e: dst=i} w_e * fx[src_e][b]
// one wave per vertex: lane = (half<<5)|batch; halves stride the edge list by 2.
__global__ __launch_bounds__(256) void k_pred_err(
        const float* __restrict__ v, const float* __restrict__ fx,
        const int* __restrict__ rp, const unsigned* __restrict__ pk,
        float* __restrict__ err) {
    int wid  = blockIdx.x * (blockDim.x >> 6) + (threadIdx.x >> 6);
    int lane = threadIdx.x & 63;
    int b = lane & 31, half = lane >> 5;
    if (wid >= N_V) return;
    int beg = rp[wid], end = rp[wid + 1];
    float sum = 0.f;
    for (int e = beg + half; e < end; e += 2) {
        unsigned p = pk[e];
        float w = bits_to_f32(p & 0xFFFF0000u);
        int nb = (int)(p & 0xFFFFu);
        sum += w * fx[(nb << 5) + b];
    }
    sum += __shfl_xor(sum, 32, 64);
    if (half == 0) {
        int idx = (wid << 5) + b;
        err[idx] = v[idx] - sum;
    }
}

// back[j][b] = sum_{e: src=j} w_e * err[dst_e][b];
// v[j][b] -= lr * (err - (1-fx^2)*back)   for non-sensory j
__global__ __launch_bounds__(256) void k_back_upd(
        const float* __restrict__ fx, const float* __restrict__ err,
        const int* __restrict__ rp, const unsigned* __restrict__ pk,
        float* __restrict__ v) {
    int wid  = blockIdx.x * (blockDim.x >> 6) + (threadIdx.x >> 6);
    int lane = threadIdx.x & 63;
    int b = lane & 31, half = lane >> 5;
    if (wid >= N_V) return;
    int beg = rp[wid], end = rp[wid + 1];
    float sum = 0.f;
    for (int e = beg + half; e < end; e += 2) {
        unsigned p = pk[e];
        float w = bits_to_f32(p & 0xFFFF0000u);
        int nb = (int)(p & 0xFFFFu);
        sum += w * err[(nb << 5) + b];
    }
    sum += __shfl_xor(sum, 32, 64);
    if (half == 0 && wid >= N_SENS) {
        int idx = (wid << 5) + b;
        float e0 = err[idx];
        float fxv = fx[idx];
        float dv = e0 - (1.f - fxv * fxv) * sum;
        v[idx] -= LR_VAL * dv;
    }
}

// internal [vertex][batch] -> output [batch][vertex] fp32
__global__ void k_out(const float* __restrict__ v, float* __restrict__ out) {
    int t = blockIdx.x * blockDim.x + threadIdx.x;
    if (t < NVB) {
        int b = t / N_V;
        int i = t - b * N_V;
        out[t] = v[(i << 5) + b];
    }
}

extern "C" void kernel_launch(void* const* d_in, const int* in_sizes, int n_in,
                              void* d_out, int out_size, void* d_ws, size_t ws_size,
                              hipStream_t stream) {
    const float* vals = (const float*)d_in[0];
    const float* wts  = (const float*)d_in[1];
    const int* ei = (const int*)d_in[2];
    const int* src = ei;
    const int* dst = ei + N_E;
    float* out = (float*)d_out;

    // ws layout (~4.6 MB)
    float* v_cur = (float*)d_ws;                  // 64000
    float* fx    = v_cur + NVB;                   // 64000
    float* err   = fx + NVB;                      // 64000
    int* rp_dst  = (int*)(err + NVB);             // 2048
    int* rp_src  = rp_dst + 2048;                 // 2048
    int* cur_dst = rp_src + 2048;                 // 2048
    int* cur_src = cur_dst + 2048;                // 2048 (contiguous: zeroed together)
    unsigned* pk_dst = (unsigned*)(cur_src + 2048);   // 500000
    unsigned* pk_src = pk_dst + N_E;                  // 500000

    const int EB = (N_E + 255) / 256;

    k_zero_i32<<<16, 256, 0, stream>>>(cur_dst, 4096);
    k_hist<<<EB, 256, 0, stream>>>(src, dst, cur_dst, cur_src);
    k_scan<<<1, 1024, 0, stream>>>(cur_dst, rp_dst, cur_src, rp_src);
    k_scatter<<<EB, 256, 0, stream>>>(src, dst, wts, cur_dst, cur_src,
                                      pk_dst, pk_src);
    k_cast_in<<<250, 256, 0, stream>>>(vals, v_cur);

    for (int t = 0; t < T_STEPS; ++t) {
        k_fx<<<250, 256, 0, stream>>>(v_cur, fx);
        k_pred_err<<<500, 256, 0, stream>>>(v_cur, fx, rp_dst, pk_dst, err);
        k_back_upd<<<500, 256, 0, stream>>>(fx, err, rp_src, pk_src, v_cur);
    }
    k_out<<<250, 256, 0, stream>>>(v_cur, out);
}

// Round 4
// 496.744 us; speedup vs baseline: 1.1920x; 1.1920x over previous
//
#include <hip/hip_runtime.h>
#include <hip/hip_bf16.h>

// PCGraphConv: iterative predictive-coding message passing.
// N_V=2000, N_E=500000, BATCH=32, T=5, lr=0.1, sensory = first 784 vertices.
// R3: gathers staged through LDS. fx/err tables stored bf16 in
// [half][vertex][16] layout (62.5 KB per batch-half -> fits static LDS,
// 2 blocks/CU). Gather waves: 4-way edge parallelism x 16 batch lanes,
// ds_read_u16 rows (broadcast pairs, conflict-free), pk reads stream
// 4 consecutive dwords/wave/iter. Backward sweep skips sensory vertices.
// CSR entry packed (bf16(w) << 16) | neighbor, built per call (ws re-poisoned).

#define N_V     2000
#define N_SENS  784
#define N_E     500000
#define T_STEPS 5
#define LR_VAL  0.1f
#define NVB     (N_V * 32)     // 64000
#define NVH     (N_V * 16)     // 32000 (one batch-half of a table)

__device__ __forceinline__ float bits_to_f32(unsigned u) {
    union { unsigned u; float f; } c; c.u = u; return c.f;
}
__device__ __forceinline__ unsigned f32_to_bits(float f) {
    union { float f; unsigned u; } c; c.f = f; return c.u;
}
__device__ __forceinline__ unsigned short f32_to_bf16(float f) {
    unsigned u = f32_to_bits(f);
    return (unsigned short)((u + 0x7FFFu + ((u >> 16) & 1u)) >> 16);  // RNE
}
__device__ __forceinline__ float bf16_to_f32(unsigned short s) {
    return bits_to_f32((unsigned)s << 16);
}

__global__ void k_zero_i32(int* a, int n) {
    int t = blockIdx.x * blockDim.x + threadIdx.x;
    if (t < n) a[t] = 0;
}

__global__ void k_hist(const int* __restrict__ src, const int* __restrict__ dst,
                       int* cnt_dst, int* cnt_src) {
    int e = blockIdx.x * blockDim.x + threadIdx.x;
    if (e < N_E) {
        atomicAdd(&cnt_dst[dst[e]], 1);
        atomicAdd(&cnt_src[src[e]], 1);
    }
}

// One block, 1024 threads: exclusive scan of 2000 counts (x2 arrays).
__global__ __launch_bounds__(1024) void k_scan(int* cnt_a, int* rp_a,
                                               int* cnt_b, int* rp_b) {
    __shared__ int sh[1024];
    int t = threadIdx.x;
    for (int pass = 0; pass < 2; ++pass) {
        int* cnt = pass ? cnt_b : cnt_a;
        int* rp  = pass ? rp_b  : rp_a;
        int i0 = 2 * t, i1 = 2 * t + 1;
        int c0 = (i0 < N_V) ? cnt[i0] : 0;
        int c1 = (i1 < N_V) ? cnt[i1] : 0;
        __syncthreads();
        sh[t] = c0 + c1;
        __syncthreads();
        for (int off = 1; off < 1024; off <<= 1) {
            int v = (t >= off) ? sh[t - off] : 0;
            __syncthreads();
            sh[t] += v;
            __syncthreads();
        }
        int incl = sh[t];
        int e0 = incl - (c0 + c1);
        int e1 = e0 + c0;
        if (i0 <= N_V) rp[i0] = e0;
        if (i1 <= N_V) rp[i1] = e1;
        if (i0 < N_V) cnt[i0] = e0;
        if (i1 < N_V) cnt[i1] = e1;
    }
}

// Build packed CSR entries: (bf16_weight_bits << 16) | neighbor_vertex.
__global__ void k_scatter(const int* __restrict__ src, const int* __restrict__ dst,
                          const float* __restrict__ w,
                          int* cur_dst, int* cur_src,
                          unsigned* __restrict__ pk_dst, unsigned* __restrict__ pk_src) {
    int e = blockIdx.x * blockDim.x + threadIdx.x;
    if (e < N_E) {
        int s = src[e], d = dst[e];
        unsigned wbits = (unsigned)f32_to_bf16(w[e]);
        int p = atomicAdd(&cur_dst[d], 1);
        pk_dst[p] = (wbits << 16) | (unsigned)s;
        int q = atomicAdd(&cur_src[s], 1);
        pk_src[q] = (wbits << 16) | (unsigned)d;
    }
}

// input [batch][vertex] fp32 -> internal [vertex][32] fp32
__global__ void k_cast_in(const float* __restrict__ vin, float* __restrict__ v) {
    int t = blockIdx.x * blockDim.x + threadIdx.x;
    if (t < NVB) {
        int i = t >> 5, b = t & 31;
        v[t] = vin[b * N_V + i];
    }
}

// fx table: bf16, layout [half][vertex][16]
__global__ void k_fx(const float* __restrict__ v, unsigned short* __restrict__ fx) {
    int t = blockIdx.x * blockDim.x + threadIdx.x;
    if (t < NVB) {
        int i = t >> 5, b = t & 31;
        int h = b >> 4, b16 = b & 15;
        fx[h * NVH + i * 16 + b16] = f32_to_bf16(tanhf(v[t]));
    }
}

// err[i][b] = v[i][b] - sum_{e: dst=i} w_e * fx[src_e][b]
// grid: 2 halves x 250 vgroups; block 256 = 4 waves; 8 vertices/block,
// 2 vertices/wave; lane = (epar<<4)|b16, epar strides the edge list by 4.
__global__ __launch_bounds__(256) void k_pred_err(
        const float* __restrict__ v, const unsigned short* __restrict__ fx,
        const int* __restrict__ rp, const unsigned* __restrict__ pk,
        unsigned short* __restrict__ err) {
    __shared__ unsigned short tab[NVH];   // 62.5 KB
    int h  = blockIdx.x / 250;
    int vg = blockIdx.x % 250;
    // stage fx half into LDS (sequential uint4)
    {
        const uint4* g = (const uint4*)(fx + h * NVH);
        uint4* l = (uint4*)tab;
        for (int i = threadIdx.x; i < NVH / 8; i += 256) l[i] = g[i];
    }
    __syncthreads();
    int wave = threadIdx.x >> 6;
    int lane = threadIdx.x & 63;
    int b16 = lane & 15, epar = lane >> 4;
    for (int k = 0; k < 2; ++k) {
        int vid = vg * 8 + wave * 2 + k;
        int beg = rp[vid], end = rp[vid + 1];
        float sum = 0.f;
        for (int e = beg + epar; e < end; e += 4) {
            unsigned p = pk[e];
            float w = bits_to_f32(p & 0xFFFF0000u);
            int nb = (int)(p & 0xFFFFu);
            sum += w * bf16_to_f32(tab[nb * 16 + b16]);
        }
        sum += __shfl_xor(sum, 16, 64);
        sum += __shfl_xor(sum, 32, 64);
        if (epar == 0) {
            float vo = v[(vid << 5) + h * 16 + b16];
            err[h * NVH + vid * 16 + b16] = f32_to_bf16(vo - sum);
        }
    }
}

// back[j][b] = sum_{e: src=j} w_e * err[dst_e][b];
// v[j][b] -= lr * (err_j - (1-fx_j^2)*back)   only for j >= N_SENS.
// grid: 2 halves x 152 vgroups over vertices 784..1999.
__global__ __launch_bounds__(256) void k_back_upd(
        const unsigned short* __restrict__ fx, const unsigned short* __restrict__ err,
        const int* __restrict__ rp, const unsigned* __restrict__ pk,
        float* __restrict__ v) {
    __shared__ unsigned short tab[NVH];   // err half, 62.5 KB
    int h  = blockIdx.x / 152;
    int vg = blockIdx.x % 152;
    {
        const uint4* g = (const uint4*)(err + h * NVH);
        uint4* l = (uint4*)tab;
        for (int i = threadIdx.x; i < NVH / 8; i += 256) l[i] = g[i];
    }
    __syncthreads();
    int wave = threadIdx.x >> 6;
    int lane = threadIdx.x & 63;
    int b16 = lane & 15, epar = lane >> 4;
    for (int k = 0; k < 2; ++k) {
        int vid = N_SENS + vg * 8 + wave * 2 + k;
        if (vid >= N_V) continue;
        int beg = rp[vid], end = rp[vid + 1];
        float sum = 0.f;
        for (int e = beg + epar; e < end; e += 4) {
            unsigned p = pk[e];
            float w = bits_to_f32(p & 0xFFFF0000u);
            int nb = (int)(p & 0xFFFFu);
            sum += w * bf16_to_f32(tab[nb * 16 + b16]);
        }
        sum += __shfl_xor(sum, 16, 64);
        sum += __shfl_xor(sum, 32, 64);
        if (epar == 0) {
            float e0  = bf16_to_f32(tab[vid * 16 + b16]);      // own err (same half)
            float fxv = bf16_to_f32(fx[h * NVH + vid * 16 + b16]);
            float dv = e0 - (1.f - fxv * fxv) * sum;
            v[(vid << 5) + h * 16 + b16] -= LR_VAL * dv;
        }
    }
}

// internal [vertex][32] -> output [batch][vertex] fp32
__global__ void k_out(const float* __restrict__ v, float* __restrict__ out) {
    int t = blockIdx.x * blockDim.x + threadIdx.x;
    if (t < NVB) {
        int b = t / N_V;
        int i = t - b * N_V;
        out[t] = v[(i << 5) + b];
    }
}

extern "C" void kernel_launch(void* const* d_in, const int* in_sizes, int n_in,
                              void* d_out, int out_size, void* d_ws, size_t ws_size,
                              hipStream_t stream) {
    const float* vals = (const float*)d_in[0];
    const float* wts  = (const float*)d_in[1];
    const int* ei = (const int*)d_in[2];
    const int* src = ei;
    const int* dst = ei + N_E;
    float* out = (float*)d_out;

    // ws layout (~4.5 MB)
    float* v_cur = (float*)d_ws;                       // 64000 f32
    unsigned short* fx_g  = (unsigned short*)(v_cur + NVB);   // 64000 bf16
    unsigned short* err_g = fx_g + NVB;                       // 64000 bf16
    int* rp_dst  = (int*)(err_g + NVB);                // 2048
    int* rp_src  = rp_dst + 2048;                      // 2048
    int* cur_dst = rp_src + 2048;                      // 2048
    int* cur_src = cur_dst + 2048;                     // 2048 (zeroed together)
    unsigned* pk_dst = (unsigned*)(cur_src + 2048);    // 500000
    unsigned* pk_src = pk_dst + N_E;                   // 500000

    const int EB = (N_E + 255) / 256;

    k_zero_i32<<<16, 256, 0, stream>>>(cur_dst, 4096);
    k_hist<<<EB, 256, 0, stream>>>(src, dst, cur_dst, cur_src);
    k_scan<<<1, 1024, 0, stream>>>(cur_dst, rp_dst, cur_src, rp_src);
    k_scatter<<<EB, 256, 0, stream>>>(src, dst, wts, cur_dst, cur_src,
                                      pk_dst, pk_src);
    k_cast_in<<<250, 256, 0, stream>>>(vals, v_cur);

    for (int t = 0; t < T_STEPS; ++t) {
        k_fx<<<250, 256, 0, stream>>>(v_cur, fx_g);
        k_pred_err<<<500, 256, 0, stream>>>(v_cur, fx_g, rp_dst, pk_dst, err_g);
        k_back_upd<<<304, 256, 0, stream>>>(fx_g, err_g, rp_src, pk_src, v_cur);
    }
    k_out<<<250, 256, 0, stream>>>(v_cur, out);
}